// Round 12
// baseline (167.458 us; speedup 1.0000x reference)
//
#include <hip/hip_runtime.h>

#define M_NODES 50000
#define E_EDGES 800000
#define K_DIM 512
#define N_DIM 256
#define CAP 64
#define NGB 782          // gemm blocks per N-half (ceil(50000/64))
#define GRID25 (NGB * 5) // 1 gemm + 4 companion blocks per group
#define GATB 3125        // gather blocks per half (50000/16)

typedef __attribute__((ext_vector_type(8))) short short8;
typedef __attribute__((ext_vector_type(4))) float f32x4;

__device__ __forceinline__ unsigned short f2bf(float f) {
    unsigned int u = __float_as_uint(f);
    unsigned int r = (u + 0x7fffu + ((u >> 16) & 1u)) >> 16;
    return (unsigned short)r;
}

__device__ __forceinline__ void gload_lds16(const void* gp, void* lp) {
    __builtin_amdgcn_global_load_lds(
        (const __attribute__((address_space(1))) unsigned int*)gp,
        (__attribute__((address_space(3))) unsigned int*)lp,
        16, 0, 0);
}

// ---------------- k1: cast W -> WT[n][k] bf16  +  zero cnt ----------------
__global__ __launch_bounds__(256) void prep_kernel(const float* __restrict__ Wm,
                                                   unsigned short* __restrict__ WT,
                                                   int* __restrict__ cnt) {
    const int bid = blockIdx.x;
    if (bid < 512) {
        const int idx = bid * 256 + threadIdx.x;      // 131072 = K*N
        const int k = idx & (K_DIM - 1);
        const int n = idx >> 9;
        WT[(size_t)n * K_DIM + k] = f2bf(Wm[(size_t)k * N_DIM + n]);
    } else {
        const int i = (bid - 512) * 256 + threadIdx.x;
        if (i < M_NODES) cnt[i] = 0;
    }
}

// ---------------- shared device bodies ----------------
__device__ __forceinline__ void fill_body(int fid, int tid,
                                          const int* __restrict__ src,
                                          const int* __restrict__ dst,
                                          const float* __restrict__ w,
                                          int* __restrict__ cnt,
                                          int2* __restrict__ edata) {
    const int e = fid * 256 + tid;
    if (e < E_EDGES) {
        const int d = dst[e];
        const int pos = atomicAdd(&cnt[d], 1);
        if (pos < CAP) edata[(size_t)d * CAP + pos] = make_int2(src[e], __float_as_int(w[e]));
    }
}

// Half-width GEMM: 64 rows x 128 cols per block, BK=32, 256 threads (4 waves).
// Granule-major LDS (slot = g*ROWS + row) -> all LDS traffic conflict-free.
__device__ __forceinline__ void gemm_body(const int n0, const int grp, const int tid,
                                          short* AsmB, short* BsmB,
                                          const float* __restrict__ x,
                                          const unsigned short* __restrict__ WT,
                                          const float* __restrict__ bv,
                                          unsigned short* __restrict__ h) {
    const int m0 = grp * 64;
    const int wv = tid >> 6;        // wave 0..3 -> cols n0 + wv*32
    const int lane = tid & 63;
    const int l15 = lane & 15;
    const int kq = lane >> 4;       // k-granule 0..3

    f32x4 acc[4][2];
    #pragma unroll
    for (int fm = 0; fm < 4; ++fm)
        #pragma unroll
        for (int fn = 0; fn < 2; ++fn)
            #pragma unroll
            for (int r = 0; r < 4; ++r) acc[fm][fn][r] = 0.f;

    float bb[2];
    #pragma unroll
    for (int fn = 0; fn < 2; ++fn) bb[fn] = bv[n0 + wv * 32 + fn * 16 + l15];

    // A staging: thread -> (row = tid>>2, granule = tid&3); coalesced 128B per 4 lanes
    const int arow = tid >> 2;      // 0..63
    const int ag = tid & 3;
    int xr = m0 + arow;
    if (xr >= M_NODES) xr = M_NODES - 1;
    const float* xp = x + (size_t)xr * K_DIM + ag * 8;
    const int awoff = (ag * 64 + arow) * 8;   // granule-major slot * 8 shorts

    float4 a4[2];

    auto stageB = [&](int buf, int k0) {
        #pragma unroll
        for (int r = 0; r < 2; ++r) {
            const int slot = r * 256 + tid;   // 0..511 = 128 n x 4 g, granule-major
            const int n = slot & 127;
            const int g = slot >> 7;
            gload_lds16(WT + (size_t)(n0 + n) * K_DIM + k0 + g * 8,
                        BsmB + buf * 4096 + slot * 8);
        }
    };
    auto loadA = [&](int k0) {
        a4[0] = *reinterpret_cast<const float4*>(xp + k0);
        a4[1] = *reinterpret_cast<const float4*>(xp + k0 + 4);
    };
    auto writeA = [&](int buf) {
        short8 s0;
        s0[0] = (short)f2bf(a4[0].x); s0[1] = (short)f2bf(a4[0].y);
        s0[2] = (short)f2bf(a4[0].z); s0[3] = (short)f2bf(a4[0].w);
        s0[4] = (short)f2bf(a4[1].x); s0[5] = (short)f2bf(a4[1].y);
        s0[6] = (short)f2bf(a4[1].z); s0[7] = (short)f2bf(a4[1].w);
        *reinterpret_cast<short8*>(AsmB + buf * 2048 + awoff) = s0;
    };
    auto compute = [&](int buf) {
        short8 af[4], bf_[2];
        #pragma unroll
        for (int fm = 0; fm < 4; ++fm)
            af[fm] = *reinterpret_cast<const short8*>(AsmB + buf * 2048 + (kq * 64 + fm * 16 + l15) * 8);
        #pragma unroll
        for (int fn = 0; fn < 2; ++fn)
            bf_[fn] = *reinterpret_cast<const short8*>(BsmB + buf * 4096 + (kq * 128 + wv * 32 + fn * 16 + l15) * 8);
        #pragma unroll
        for (int fm = 0; fm < 4; ++fm)
            #pragma unroll
            for (int fn = 0; fn < 2; ++fn)
                acc[fm][fn] = __builtin_amdgcn_mfma_f32_16x16x32_bf16(af[fm], bf_[fn], acc[fm][fn], 0, 0, 0);
    };

    // prologue
    stageB(0, 0);
    loadA(0);
    writeA(0);
    __syncthreads();

    #pragma unroll
    for (int t = 0; t < 16; ++t) {
        const int buf = t & 1;
        if (t < 15) {
            stageB(buf ^ 1, (t + 1) * 32);
            loadA((t + 1) * 32);
        }
        compute(buf);
        if (t < 15) writeA(buf ^ 1);
        __syncthreads();
    }

    // epilogue: C layout col=lane&15, row=(lane>>4)*4+r
    #pragma unroll
    for (int fm = 0; fm < 4; ++fm) {
        const int gm = m0 + fm * 16 + kq * 4;
        #pragma unroll
        for (int r = 0; r < 4; ++r) {
            if (gm + r < M_NODES) {
                #pragma unroll
                for (int fn = 0; fn < 2; ++fn) {
                    const int gn = n0 + wv * 32 + fn * 16 + l15;
                    h[(size_t)(gm + r) * N_DIM + gn] = f2bf(acc[fm][fn][r] + bb[fn]);
                }
            }
        }
    }
}

#define ACC8(v, wq)                                        \
    acc[0] += wq * __uint_as_float(v.x << 16);             \
    acc[1] += wq * __uint_as_float(v.x & 0xffff0000u);     \
    acc[2] += wq * __uint_as_float(v.y << 16);             \
    acc[3] += wq * __uint_as_float(v.y & 0xffff0000u);     \
    acc[4] += wq * __uint_as_float(v.z << 16);             \
    acc[5] += wq * __uint_as_float(v.z & 0xffff0000u);     \
    acc[6] += wq * __uint_as_float(v.w << 16);             \
    acc[7] += wq * __uint_as_float(v.w & 0xffff0000u);

// Gather one 128-col half: 16 lanes/node, 16 nodes/block, 8-edge unroll.
__device__ __forceinline__ void gather_body(const unsigned short* __restrict__ h,
                                            const int* __restrict__ cnt,
                                            const int2* __restrict__ edata,
                                            float* __restrict__ out,
                                            int gid, int tid, int halfsel) {
    const int node = gid * 16 + (tid >> 4);
    const int lane = tid & 15;

    int m = cnt[node];
    if (m > CAP) m = CAP;
    const int2* ep = edata + (size_t)node * CAP;

    float acc[8];
    #pragma unroll
    for (int i = 0; i < 8; ++i) acc[i] = 0.f;

    const unsigned short* hb = h + halfsel * 128 + lane * 8;

    int j = 0;
    for (; j + 7 < m; j += 8) {
        int4 e2[4];
        #pragma unroll
        for (int q = 0; q < 4; ++q)
            e2[q] = *reinterpret_cast<const int4*>(ep + j + q * 2);
        uint4 v[8];
        #pragma unroll
        for (int q = 0; q < 4; ++q) {
            v[q * 2]     = *reinterpret_cast<const uint4*>(hb + (size_t)e2[q].x * N_DIM);
            v[q * 2 + 1] = *reinterpret_cast<const uint4*>(hb + (size_t)e2[q].z * N_DIM);
        }
        #pragma unroll
        for (int q = 0; q < 4; ++q) {
            const float w0 = __int_as_float(e2[q].y);
            const float w1 = __int_as_float(e2[q].w);
            ACC8(v[q * 2], w0);
            ACC8(v[q * 2 + 1], w1);
        }
    }
    for (; j + 1 < m; j += 2) {
        const int4 e2 = *reinterpret_cast<const int4*>(ep + j);
        const uint4 v0 = *reinterpret_cast<const uint4*>(hb + (size_t)e2.x * N_DIM);
        const uint4 v1 = *reinterpret_cast<const uint4*>(hb + (size_t)e2.z * N_DIM);
        ACC8(v0, __int_as_float(e2.y));
        ACC8(v1, __int_as_float(e2.w));
    }
    if (j < m) {
        const int2 e0 = ep[j];
        const uint4 v = *reinterpret_cast<const uint4*>(hb + (size_t)e0.x * N_DIM);
        ACC8(v, __int_as_float(e0.y));
    }

    float* op = out + (size_t)node * N_DIM + halfsel * 128 + lane * 8;
    *reinterpret_cast<float4*>(op) = make_float4(acc[0], acc[1], acc[2], acc[3]);
    *reinterpret_cast<float4*>(op + 4) = make_float4(acc[4], acc[5], acc[6], acc[7]);
}

// ---------------- k2: gemm cols [0,128) + bucket fill ----------------
__global__ __launch_bounds__(256) void k2_gemm0_fill(const float* __restrict__ x,
                                                     const unsigned short* __restrict__ WT,
                                                     const float* __restrict__ bv,
                                                     unsigned short* __restrict__ h,
                                                     const int* __restrict__ src,
                                                     const int* __restrict__ dst,
                                                     const float* __restrict__ w,
                                                     int* __restrict__ cnt,
                                                     int2* __restrict__ edata) {
    __shared__ short AsmB[2 * 64 * 32];
    __shared__ short BsmB[2 * 128 * 32];
    const int bid = blockIdx.x;
    const int tid = threadIdx.x;
    const int r5 = bid % 5;
    const int grp = bid / 5;
    if (r5 == 0) gemm_body(0, grp, tid, AsmB, BsmB, x, WT, bv, h);
    else fill_body(grp * 4 + r5 - 1, tid, src, dst, w, cnt, edata);
}

// ---------------- k3: gemm cols [128,256) + gather half 0 ----------------
__global__ __launch_bounds__(256) void k3_gemm1_gather0(const float* __restrict__ x,
                                                        const unsigned short* __restrict__ WT,
                                                        const float* __restrict__ bv,
                                                        unsigned short* __restrict__ h,
                                                        const int* __restrict__ cnt,
                                                        const int2* __restrict__ edata,
                                                        float* __restrict__ out) {
    __shared__ short AsmB[2 * 64 * 32];
    __shared__ short BsmB[2 * 128 * 32];
    const int bid = blockIdx.x;
    const int tid = threadIdx.x;
    const int r5 = bid % 5;
    const int grp = bid / 5;
    if (r5 == 0) {
        gemm_body(128, grp, tid, AsmB, BsmB, x, WT, bv, h);
    } else {
        const int gid = grp * 4 + r5 - 1;
        if (gid < GATB) gather_body(h, cnt, edata, out, gid, tid, 0);
    }
}

// ---------------- k4: gather half 1 ----------------
__global__ __launch_bounds__(256) void k4_gather1(const unsigned short* __restrict__ h,
                                                  const int* __restrict__ cnt,
                                                  const int2* __restrict__ edata,
                                                  float* __restrict__ out) {
    gather_body(h, cnt, edata, out, blockIdx.x, threadIdx.x, 1);
}

extern "C" void kernel_launch(void* const* d_in, const int* in_sizes, int n_in,
                              void* d_out, int out_size, void* d_ws, size_t ws_size,
                              hipStream_t stream) {
    const float* x   = (const float*)d_in[0];
    const int*   src = (const int*)d_in[1];
    const int*   dst = (const int*)d_in[2];
    const float* w   = (const float*)d_in[3];
    const float* Wm  = (const float*)d_in[4];
    const float* b   = (const float*)d_in[5];
    float* out = (float*)d_out;

    // Workspace layout (bytes)
    char* ws = (char*)d_ws;
    unsigned short* WT = (unsigned short*)(ws + 0);            //    262,144
    unsigned short* h  = (unsigned short*)(ws + 262144);       // 25,600,000
    int*  cnt   = (int*)(ws + 25862144);                       //    200,000
    int2* edata = (int2*)(ws + 26062144);                      // 25,600,000 (end ~51.7 MB)

    // k1: cast W + zero cnt
    prep_kernel<<<512 + (M_NODES + 255) / 256, 256, 0, stream>>>(Wm, WT, cnt);

    // k2: gemm cols 0-127 + bucket fill (fill completes here)
    k2_gemm0_fill<<<GRID25, 256, 0, stream>>>(x, WT, b, h, src, dst, w, cnt, edata);

    // k3: gemm cols 128-255 overlapped with gather of cols 0-127
    k3_gemm1_gather0<<<GRID25, 256, 0, stream>>>(x, WT, b, h, cnt, edata, out);

    // k4: gather cols 128-255
    k4_gather1<<<GATB, 256, 0, stream>>>(h, cnt, edata, out);
}

// Round 13
// 152.263 us; speedup vs baseline: 1.0998x; 1.0998x over previous
//
#include <hip/hip_runtime.h>

#define M_NODES 50000
#define E_EDGES 800000
#define K_DIM 512
#define N_DIM 256
#define CAP 64
#define NGB 782          // gemm groups (ceil(50000/64))
#define GRID (NGB * 3)   // 1 gemm + 2 fill blocks per group

typedef __attribute__((ext_vector_type(8))) short short8;
typedef __attribute__((ext_vector_type(4))) float f32x4;

__device__ __forceinline__ unsigned short f2bf(float f) {
    unsigned int u = __float_as_uint(f);
    unsigned int r = (u + 0x7fffu + ((u >> 16) & 1u)) >> 16;
    return (unsigned short)r;
}

__device__ __forceinline__ void gload_lds16(const void* gp, void* lp) {
    __builtin_amdgcn_global_load_lds(
        (const __attribute__((address_space(1))) unsigned int*)gp,
        (__attribute__((address_space(3))) unsigned int*)lp,
        16, 0, 0);
}

// ---------------- k1: cast W -> WT[n][k] bf16  +  zero cnt ----------------
__global__ __launch_bounds__(256) void prep_kernel(const float* __restrict__ Wm,
                                                   unsigned short* __restrict__ WT,
                                                   int* __restrict__ cnt) {
    const int bid = blockIdx.x;
    if (bid < 512) {
        const int idx = bid * 256 + threadIdx.x;      // 131072 = K*N
        const int k = idx & (K_DIM - 1);
        const int n = idx >> 9;
        WT[(size_t)n * K_DIM + k] = f2bf(Wm[(size_t)k * N_DIM + n]);
    } else {
        const int i = (bid - 512) * 256 + threadIdx.x;
        if (i < M_NODES) cnt[i] = 0;
    }
}

// ---------------- k2: GEMM + interleaved bucket fill ----------------
// bid%3==0 -> gemm group bid/3: BM=64, BN=256, BK=32, 512 threads, 40 KB LDS (4 blocks/CU).
// LDS layout GRANULE-MAJOR (slot = g*ROWS + row): B staged by global_load_lds with linear
// dest + (n,g) source mapping; A ds_write at slot=tid (contiguous). All LDS traffic
// conflict-free (r11 PMC: 0 conflicts with this read pattern).
// bid%3!=0 -> fill block (512 edges), resident alongside gemm blocks on the same CU.
__global__ __launch_bounds__(512) void gemm_fill(const float* __restrict__ x,
                                                 const unsigned short* __restrict__ WT,
                                                 const float* __restrict__ b,
                                                 unsigned short* __restrict__ h,
                                                 const int* __restrict__ src,
                                                 const int* __restrict__ dst,
                                                 const float* __restrict__ w,
                                                 int* __restrict__ cnt,
                                                 int2* __restrict__ edata) {
    __shared__ short Asm[2][256 * 8];     //  8 KB: slot = g*64 + row
    __shared__ short Bsm[2][1024 * 8];    // 32 KB: slot = g*256 + n

    const int bid = blockIdx.x;
    const int tid = threadIdx.x;
    const int r3 = bid % 3;
    const int grp = bid / 3;

    if (r3 != 0) {
        // ---- bucket fill (cnt pre-zeroed by prep) ----
        const int fid = grp * 2 + (r3 - 1);
        const int e = fid * 512 + tid;
        if (e < E_EDGES) {
            const int d = dst[e];
            const int pos = atomicAdd(&cnt[d], 1);
            if (pos < CAP) edata[(size_t)d * CAP + pos] = make_int2(src[e], __float_as_int(w[e]));
        }
        return;
    }

    const int m0 = grp * 64;
    const int wv = tid >> 6;        // wave 0..7
    const int wr = wv >> 2;         // m-half: rows wr*32..
    const int wc = wv & 3;          // n-quarter: cols wc*64..
    const int lane = tid & 63;
    const int l15 = lane & 15;
    const int kq = lane >> 4;       // k-granule 0..3

    f32x4 acc[2][4];
    #pragma unroll
    for (int fm = 0; fm < 2; ++fm)
        #pragma unroll
        for (int fn = 0; fn < 4; ++fn)
            #pragma unroll
            for (int r = 0; r < 4; ++r) acc[fm][fn][r] = 0.f;

    float bb[4];
    #pragma unroll
    for (int fn = 0; fn < 4; ++fn) bb[fn] = b[wc * 64 + fn * 16 + l15];

    // A staging (threads 0..255): row = tid&63, granule = tid>>6 -> LDS slot = tid.
    const int arow = tid & 63;
    const int ag = (tid >> 6) & 3;
    int xr = m0 + arow;
    if (xr >= M_NODES) xr = M_NODES - 1;
    const float* xp = x + (size_t)xr * K_DIM + ag * 8;
    const bool do_a = (tid < 256);

    float4 a4[2];

    auto stageB = [&](int buf, int k0) {
        #pragma unroll
        for (int r = 0; r < 2; ++r) {
            const int slot = r * 512 + tid;       // 0..1023, granule-major dest
            const int n = slot & 255;
            const int g = slot >> 8;
            gload_lds16(WT + (size_t)n * K_DIM + k0 + g * 8, &Bsm[buf][slot * 8]);
        }
    };
    auto loadA = [&](int k0) {
        if (do_a) {
            a4[0] = *reinterpret_cast<const float4*>(xp + k0);
            a4[1] = *reinterpret_cast<const float4*>(xp + k0 + 4);
        }
    };
    auto writeA = [&](int buf) {
        if (do_a) {
            short8 s0;
            s0[0] = (short)f2bf(a4[0].x); s0[1] = (short)f2bf(a4[0].y);
            s0[2] = (short)f2bf(a4[0].z); s0[3] = (short)f2bf(a4[0].w);
            s0[4] = (short)f2bf(a4[1].x); s0[5] = (short)f2bf(a4[1].y);
            s0[6] = (short)f2bf(a4[1].z); s0[7] = (short)f2bf(a4[1].w);
            *reinterpret_cast<short8*>(&Asm[buf][tid * 8]) = s0;   // slot = ag*64+arow = tid
        }
    };
    auto compute = [&](int buf) {
        short8 af[2], bf_[4];
        #pragma unroll
        for (int fm = 0; fm < 2; ++fm)
            af[fm] = *reinterpret_cast<const short8*>(&Asm[buf][(kq * 64 + wr * 32 + fm * 16 + l15) * 8]);
        #pragma unroll
        for (int fn = 0; fn < 4; ++fn)
            bf_[fn] = *reinterpret_cast<const short8*>(&Bsm[buf][(kq * 256 + wc * 64 + fn * 16 + l15) * 8]);
        #pragma unroll
        for (int fm = 0; fm < 2; ++fm)
            #pragma unroll
            for (int fn = 0; fn < 4; ++fn)
                acc[fm][fn] = __builtin_amdgcn_mfma_f32_16x16x32_bf16(af[fm], bf_[fn], acc[fm][fn], 0, 0, 0);
    };

    // prologue
    stageB(0, 0);
    loadA(0);
    writeA(0);
    __syncthreads();

    #pragma unroll
    for (int t = 0; t < 16; ++t) {
        const int buf = t & 1;
        if (t < 15) {
            stageB(buf ^ 1, (t + 1) * 32);   // async global->LDS into other buffer
            loadA((t + 1) * 32);             // issue A loads early (T14)
        }
        compute(buf);
        if (t < 15) writeA(buf ^ 1);         // cvt + ds_write after compute
        __syncthreads();
    }

    // epilogue: C layout col=lane&15, row=(lane>>4)*4+r
    #pragma unroll
    for (int fm = 0; fm < 2; ++fm) {
        const int gm = m0 + wr * 32 + fm * 16 + kq * 4;
        #pragma unroll
        for (int r = 0; r < 4; ++r) {
            if (gm + r < M_NODES) {
                #pragma unroll
                for (int fn = 0; fn < 4; ++fn) {
                    const int gn = wc * 64 + fn * 16 + l15;
                    h[(size_t)(gm + r) * N_DIM + gn] = f2bf(acc[fm][fn][r] + bb[fn]);
                }
            }
        }
    }
}

// ---------------- k3: gather, 32 lanes/node, 8-edge unroll, int4 edge loads ----------------
#define ACC8(v, wq)                                        \
    acc[0] += wq * __uint_as_float(v.x << 16);             \
    acc[1] += wq * __uint_as_float(v.x & 0xffff0000u);     \
    acc[2] += wq * __uint_as_float(v.y << 16);             \
    acc[3] += wq * __uint_as_float(v.y & 0xffff0000u);     \
    acc[4] += wq * __uint_as_float(v.z << 16);             \
    acc[5] += wq * __uint_as_float(v.z & 0xffff0000u);     \
    acc[6] += wq * __uint_as_float(v.w << 16);             \
    acc[7] += wq * __uint_as_float(v.w & 0xffff0000u);

__global__ __launch_bounds__(256) void gather_kernel(const unsigned short* __restrict__ h,
                                                     const int* __restrict__ cnt,
                                                     const int2* __restrict__ edata,
                                                     float* __restrict__ out) {
    const int node = blockIdx.x * 8 + (threadIdx.x >> 5);
    const int lane = threadIdx.x & 31;

    int m = cnt[node];
    if (m > CAP) m = CAP;
    const int2* ep = edata + (size_t)node * CAP;

    float acc[8];
    #pragma unroll
    for (int i = 0; i < 8; ++i) acc[i] = 0.f;

    const unsigned short* hb = h + lane * 8;

    int j = 0;
    for (; j + 7 < m; j += 8) {
        int4 e2[4];
        #pragma unroll
        for (int q = 0; q < 4; ++q)
            e2[q] = *reinterpret_cast<const int4*>(ep + j + q * 2);
        uint4 v[8];
        #pragma unroll
        for (int q = 0; q < 4; ++q) {
            v[q * 2]     = *reinterpret_cast<const uint4*>(hb + (size_t)e2[q].x * N_DIM);
            v[q * 2 + 1] = *reinterpret_cast<const uint4*>(hb + (size_t)e2[q].z * N_DIM);
        }
        #pragma unroll
        for (int q = 0; q < 4; ++q) {
            const float w0 = __int_as_float(e2[q].y);
            const float w1 = __int_as_float(e2[q].w);
            ACC8(v[q * 2], w0);
            ACC8(v[q * 2 + 1], w1);
        }
    }
    for (; j + 1 < m; j += 2) {
        const int4 e2 = *reinterpret_cast<const int4*>(ep + j);
        const uint4 v0 = *reinterpret_cast<const uint4*>(hb + (size_t)e2.x * N_DIM);
        const uint4 v1 = *reinterpret_cast<const uint4*>(hb + (size_t)e2.z * N_DIM);
        ACC8(v0, __int_as_float(e2.y));
        ACC8(v1, __int_as_float(e2.w));
    }
    if (j < m) {
        const int2 e0 = ep[j];
        const uint4 v = *reinterpret_cast<const uint4*>(hb + (size_t)e0.x * N_DIM);
        ACC8(v, __int_as_float(e0.y));
    }

    float* op = out + (size_t)node * N_DIM + lane * 8;
    *reinterpret_cast<float4*>(op) = make_float4(acc[0], acc[1], acc[2], acc[3]);
    *reinterpret_cast<float4*>(op + 4) = make_float4(acc[4], acc[5], acc[6], acc[7]);
}

extern "C" void kernel_launch(void* const* d_in, const int* in_sizes, int n_in,
                              void* d_out, int out_size, void* d_ws, size_t ws_size,
                              hipStream_t stream) {
    const float* x   = (const float*)d_in[0];
    const int*   src = (const int*)d_in[1];
    const int*   dst = (const int*)d_in[2];
    const float* w   = (const float*)d_in[3];
    const float* Wm  = (const float*)d_in[4];
    const float* b   = (const float*)d_in[5];
    float* out = (float*)d_out;

    // Workspace layout (bytes)
    char* ws = (char*)d_ws;
    unsigned short* WT = (unsigned short*)(ws + 0);            //    262,144
    unsigned short* h  = (unsigned short*)(ws + 262144);       // 25,600,000
    int*  cnt   = (int*)(ws + 25862144);                       //    200,000
    int2* edata = (int2*)(ws + 26062144);                      // 25,600,000 (end ~51.7 MB)

    // k1: cast W + zero cnt
    prep_kernel<<<512 + (M_NODES + 255) / 256, 256, 0, stream>>>(Wm, WT, cnt);

    // k2: projection with interleaved bucket fill
    gemm_fill<<<GRID, 512, 0, stream>>>(x, WT, b, h, src, dst, w, cnt, edata);

    // k3: aggregate
    gather_kernel<<<M_NODES / 8, 256, 0, stream>>>(h, cnt, edata, out);
}

// Round 14
// 120.505 us; speedup vs baseline: 1.3896x; 1.2635x over previous
//
#include <hip/hip_runtime.h>

#define M_NODES 50000
#define E_EDGES 800000
#define K_DIM 512
#define N_DIM 256
#define CAP 64
#define NGB 782          // gemm groups (ceil(50000/64))
#define GRID (NGB * 3)   // 1 gemm + 2 fill blocks per group

typedef __attribute__((ext_vector_type(8))) short short8;
typedef __attribute__((ext_vector_type(4))) float f32x4;

__device__ __forceinline__ unsigned short f2bf(float f) {
    unsigned int u = __float_as_uint(f);
    unsigned int r = (u + 0x7fffu + ((u >> 16) & 1u)) >> 16;
    return (unsigned short)r;
}

__device__ __forceinline__ void gload_lds16(const void* gp, void* lp) {
    __builtin_amdgcn_global_load_lds(
        (const __attribute__((address_space(1))) unsigned int*)gp,
        (__attribute__((address_space(3))) unsigned int*)lp,
        16, 0, 0);
}

// ---------------- k1: build WTg tiled [kb][g][n][8] bf16  +  zero cnt ----------------
// WTg element d (0..131071): e = d&7, gslot = d>>3, n = gslot&255, kb4g = gslot>>8,
// k = (kb4g>>2)*32 + (kb4g&3)*8 + e. Dest writes coalesced; Wm reads L2-served (0.5 MB).
__global__ __launch_bounds__(256) void prep_kernel(const float* __restrict__ Wm,
                                                   unsigned short* __restrict__ WTg,
                                                   int* __restrict__ cnt) {
    const int bid = blockIdx.x;
    if (bid < 512) {
        const int d = bid * 256 + threadIdx.x;        // 131072 = K*N
        const int e = d & 7;
        const int gslot = d >> 3;
        const int n = gslot & 255;
        const int kb4g = gslot >> 8;
        const int k = (kb4g >> 2) * 32 + (kb4g & 3) * 8 + e;
        WTg[d] = f2bf(Wm[(size_t)k * N_DIM + n]);
    } else {
        const int i = (bid - 512) * 256 + threadIdx.x;
        if (i < M_NODES) cnt[i] = 0;
    }
}

// ---------------- k2: GEMM + interleaved bucket fill ----------------
// bid%3==0 -> gemm group bid/3: BM=64, BN=256, BK=32, 512 threads, 40 KB LDS (4 blocks/CU).
// LDS granule-major (slot = g*ROWS + row). B staged from pre-tiled WTg: source is
// lane-consecutive (fully coalesced) AND reads conflict-free. A staged with r10's
// coalesced row mapping (4 lanes = 128 B of one x row) into granule-major slots.
// bid%3!=0 -> fill block (512 edges), resident alongside gemm blocks.
__global__ __launch_bounds__(512) void gemm_fill(const float* __restrict__ x,
                                                 const unsigned short* __restrict__ WTg,
                                                 const float* __restrict__ b,
                                                 unsigned short* __restrict__ h,
                                                 const int* __restrict__ src,
                                                 const int* __restrict__ dst,
                                                 const float* __restrict__ w,
                                                 int* __restrict__ cnt,
                                                 int2* __restrict__ edata) {
    __shared__ short Asm[2][256 * 8];     //  8 KB: slot = g*64 + row
    __shared__ short Bsm[2][1024 * 8];    // 32 KB: slot = g*256 + n

    const int bid = blockIdx.x;
    const int tid = threadIdx.x;
    const int r3 = bid % 3;
    const int grp = bid / 3;

    if (r3 != 0) {
        // ---- bucket fill (cnt pre-zeroed by prep) ----
        const int fid = grp * 2 + (r3 - 1);
        const int e = fid * 512 + tid;
        if (e < E_EDGES) {
            const int d = dst[e];
            const int pos = atomicAdd(&cnt[d], 1);
            if (pos < CAP) edata[(size_t)d * CAP + pos] = make_int2(src[e], __float_as_int(w[e]));
        }
        return;
    }

    const int m0 = grp * 64;
    const int wv = tid >> 6;        // wave 0..7
    const int wr = wv >> 2;         // m-half: rows wr*32..
    const int wc = wv & 3;          // n-quarter: cols wc*64..
    const int lane = tid & 63;
    const int l15 = lane & 15;
    const int kq = lane >> 4;       // k-granule 0..3

    f32x4 acc[2][4];
    #pragma unroll
    for (int fm = 0; fm < 2; ++fm)
        #pragma unroll
        for (int fn = 0; fn < 4; ++fn)
            #pragma unroll
            for (int r = 0; r < 4; ++r) acc[fm][fn][r] = 0.f;

    float bb[4];
    #pragma unroll
    for (int fn = 0; fn < 4; ++fn) bb[fn] = b[wc * 64 + fn * 16 + l15];

    // A staging (threads 0..255): row = tid>>2 (4 lanes per row = 128 B coalesced),
    // granule = tid&3; LDS slot = ag*64 + arow (granule-major).
    const int arow = tid >> 2;      // 0..63
    const int ag = tid & 3;
    int xr = m0 + arow;
    if (xr >= M_NODES) xr = M_NODES - 1;
    const float* xp = x + (size_t)xr * K_DIM + ag * 8;
    const bool do_a = (tid < 256);
    const int aslot = (ag * 64 + arow) * 8;

    float4 a4[2];

    auto stageB = [&](int buf, int k0) {
        const unsigned short* wsrc = WTg + (size_t)(k0 >> 5) * 8192;   // kb*4*256*8
        #pragma unroll
        for (int r = 0; r < 2; ++r) {
            const int slot = r * 512 + tid;       // 0..1023, granule-major, lane-consecutive
            gload_lds16(wsrc + slot * 8, &Bsm[buf][slot * 8]);
        }
    };
    auto loadA = [&](int k0) {
        if (do_a) {
            a4[0] = *reinterpret_cast<const float4*>(xp + k0);
            a4[1] = *reinterpret_cast<const float4*>(xp + k0 + 4);
        }
    };
    auto writeA = [&](int buf) {
        if (do_a) {
            short8 s0;
            s0[0] = (short)f2bf(a4[0].x); s0[1] = (short)f2bf(a4[0].y);
            s0[2] = (short)f2bf(a4[0].z); s0[3] = (short)f2bf(a4[0].w);
            s0[4] = (short)f2bf(a4[1].x); s0[5] = (short)f2bf(a4[1].y);
            s0[6] = (short)f2bf(a4[1].z); s0[7] = (short)f2bf(a4[1].w);
            *reinterpret_cast<short8*>(&Asm[buf][aslot]) = s0;
        }
    };
    auto compute = [&](int buf) {
        short8 af[2], bf_[4];
        #pragma unroll
        for (int fm = 0; fm < 2; ++fm)
            af[fm] = *reinterpret_cast<const short8*>(&Asm[buf][(kq * 64 + wr * 32 + fm * 16 + l15) * 8]);
        #pragma unroll
        for (int fn = 0; fn < 4; ++fn)
            bf_[fn] = *reinterpret_cast<const short8*>(&Bsm[buf][(kq * 256 + wc * 64 + fn * 16 + l15) * 8]);
        #pragma unroll
        for (int fm = 0; fm < 2; ++fm)
            #pragma unroll
            for (int fn = 0; fn < 4; ++fn)
                acc[fm][fn] = __builtin_amdgcn_mfma_f32_16x16x32_bf16(af[fm], bf_[fn], acc[fm][fn], 0, 0, 0);
    };

    // prologue
    stageB(0, 0);
    loadA(0);
    writeA(0);
    __syncthreads();

    #pragma unroll
    for (int t = 0; t < 16; ++t) {
        const int buf = t & 1;
        if (t < 15) {
            stageB(buf ^ 1, (t + 1) * 32);   // async global->LDS into other buffer
            loadA((t + 1) * 32);             // issue A loads early (T14)
        }
        compute(buf);
        if (t < 15) writeA(buf ^ 1);         // cvt + ds_write after compute
        __syncthreads();
    }

    // epilogue: C layout col=lane&15, row=(lane>>4)*4+r
    #pragma unroll
    for (int fm = 0; fm < 2; ++fm) {
        const int gm = m0 + wr * 32 + fm * 16 + kq * 4;
        #pragma unroll
        for (int r = 0; r < 4; ++r) {
            if (gm + r < M_NODES) {
                #pragma unroll
                for (int fn = 0; fn < 4; ++fn) {
                    const int gn = wc * 64 + fn * 16 + l15;
                    h[(size_t)(gm + r) * N_DIM + gn] = f2bf(acc[fm][fn][r] + bb[fn]);
                }
            }
        }
    }
}

// ---------------- k3: gather, 32 lanes/node, 8-edge unroll, int4 edge loads ----------------
#define ACC8(v, wq)                                        \
    acc[0] += wq * __uint_as_float(v.x << 16);             \
    acc[1] += wq * __uint_as_float(v.x & 0xffff0000u);     \
    acc[2] += wq * __uint_as_float(v.y << 16);             \
    acc[3] += wq * __uint_as_float(v.y & 0xffff0000u);     \
    acc[4] += wq * __uint_as_float(v.z << 16);             \
    acc[5] += wq * __uint_as_float(v.z & 0xffff0000u);     \
    acc[6] += wq * __uint_as_float(v.w << 16);             \
    acc[7] += wq * __uint_as_float(v.w & 0xffff0000u);

__global__ __launch_bounds__(256) void gather_kernel(const unsigned short* __restrict__ h,
                                                     const int* __restrict__ cnt,
                                                     const int2* __restrict__ edata,
                                                     float* __restrict__ out) {
    const int node = blockIdx.x * 8 + (threadIdx.x >> 5);
    const int lane = threadIdx.x & 31;

    int m = cnt[node];
    if (m > CAP) m = CAP;
    const int2* ep = edata + (size_t)node * CAP;

    float acc[8];
    #pragma unroll
    for (int i = 0; i < 8; ++i) acc[i] = 0.f;

    const unsigned short* hb = h + lane * 8;

    int j = 0;
    for (; j + 7 < m; j += 8) {
        int4 e2[4];
        #pragma unroll
        for (int q = 0; q < 4; ++q)
            e2[q] = *reinterpret_cast<const int4*>(ep + j + q * 2);
        uint4 v[8];
        #pragma unroll
        for (int q = 0; q < 4; ++q) {
            v[q * 2]     = *reinterpret_cast<const uint4*>(hb + (size_t)e2[q].x * N_DIM);
            v[q * 2 + 1] = *reinterpret_cast<const uint4*>(hb + (size_t)e2[q].z * N_DIM);
        }
        #pragma unroll
        for (int q = 0; q < 4; ++q) {
            const float w0 = __int_as_float(e2[q].y);
            const float w1 = __int_as_float(e2[q].w);
            ACC8(v[q * 2], w0);
            ACC8(v[q * 2 + 1], w1);
        }
    }
    for (; j + 1 < m; j += 2) {
        const int4 e2 = *reinterpret_cast<const int4*>(ep + j);
        const uint4 v0 = *reinterpret_cast<const uint4*>(hb + (size_t)e2.x * N_DIM);
        const uint4 v1 = *reinterpret_cast<const uint4*>(hb + (size_t)e2.z * N_DIM);
        ACC8(v0, __int_as_float(e2.y));
        ACC8(v1, __int_as_float(e2.w));
    }
    if (j < m) {
        const int2 e0 = ep[j];
        const uint4 v = *reinterpret_cast<const uint4*>(hb + (size_t)e0.x * N_DIM);
        ACC8(v, __int_as_float(e0.y));
    }

    float* op = out + (size_t)node * N_DIM + lane * 8;
    *reinterpret_cast<float4*>(op) = make_float4(acc[0], acc[1], acc[2], acc[3]);
    *reinterpret_cast<float4*>(op + 4) = make_float4(acc[4], acc[5], acc[6], acc[7]);
}

extern "C" void kernel_launch(void* const* d_in, const int* in_sizes, int n_in,
                              void* d_out, int out_size, void* d_ws, size_t ws_size,
                              hipStream_t stream) {
    const float* x   = (const float*)d_in[0];
    const int*   src = (const int*)d_in[1];
    const int*   dst = (const int*)d_in[2];
    const float* w   = (const float*)d_in[3];
    const float* Wm  = (const float*)d_in[4];
    const float* b   = (const float*)d_in[5];
    float* out = (float*)d_out;

    // Workspace layout (bytes)
    char* ws = (char*)d_ws;
    unsigned short* WTg = (unsigned short*)(ws + 0);           //    262,144 (tiled)
    unsigned short* h   = (unsigned short*)(ws + 262144);      // 25,600,000
    int*  cnt   = (int*)(ws + 25862144);                       //    200,000
    int2* edata = (int2*)(ws + 26062144);                      // 25,600,000 (end ~51.7 MB)

    // k1: build tiled WTg + zero cnt
    prep_kernel<<<512 + (M_NODES + 255) / 256, 256, 0, stream>>>(Wm, WTg, cnt);

    // k2: projection with interleaved bucket fill
    gemm_fill<<<GRID, 512, 0, stream>>>(x, WTg, b, h, src, dst, w, cnt, edata);

    // k3: aggregate
    gather_kernel<<<M_NODES / 8, 256, 0, stream>>>(h, cnt, edata, out);
}

// Round 15
// 119.058 us; speedup vs baseline: 1.4065x; 1.0122x over previous
//
#include <hip/hip_runtime.h>

#define M_NODES 50000
#define E_EDGES 800000
#define K_DIM 512
#define N_DIM 256
#define CAP 64
#define NGB 782          // gemm groups (ceil(50000/64))
#define GRID (NGB * 3)   // 1 gemm + 2 fill blocks per group

typedef __attribute__((ext_vector_type(8))) short short8;
typedef __attribute__((ext_vector_type(4))) float f32x4;

__device__ __forceinline__ unsigned short f2bf(float f) {
    unsigned int u = __float_as_uint(f);
    unsigned int r = (u + 0x7fffu + ((u >> 16) & 1u)) >> 16;
    return (unsigned short)r;
}

__device__ __forceinline__ void gload_lds16(const void* gp, void* lp) {
    __builtin_amdgcn_global_load_lds(
        (const __attribute__((address_space(1))) unsigned int*)gp,
        (__attribute__((address_space(3))) unsigned int*)lp,
        16, 0, 0);
}

// ---------------- k1: build WTg tiled [kb][g][n][8] bf16  +  zero cnt ----------------
__global__ __launch_bounds__(256) void prep_kernel(const float* __restrict__ Wm,
                                                   unsigned short* __restrict__ WTg,
                                                   int* __restrict__ cnt) {
    const int bid = blockIdx.x;
    if (bid < 512) {
        const int d = bid * 256 + threadIdx.x;        // 131072 = K*N
        const int e = d & 7;
        const int gslot = d >> 3;
        const int n = gslot & 255;
        const int kb4g = gslot >> 8;
        const int k = (kb4g >> 2) * 32 + (kb4g & 3) * 8 + e;
        WTg[d] = f2bf(Wm[(size_t)k * N_DIM + n]);
    } else {
        const int i = (bid - 512) * 256 + threadIdx.x;
        if (i < M_NODES) cnt[i] = 0;
    }
}

// ---------------- k2: GEMM + interleaved bucket fill ----------------
// bid%3==0 -> gemm group: BM=64, BN=256, BK=32, 512 threads, 40 KB LDS (4 blocks/CU).
// B from pre-tiled WTg via global_load_lds (coalesced + conflict-free).
// A: depth-2 register pipeline (load k_{t+2} at top of iter t) + XOR-swizzled ds_write
// (slot = ag*64 + (arow ^ (ag<<1))) -> write conflicts ~0; reads use matching XOR.
// bid%3!=0 -> fill block (512 edges).
__global__ __launch_bounds__(512) void gemm_fill(const float* __restrict__ x,
                                                 const unsigned short* __restrict__ WTg,
                                                 const float* __restrict__ b,
                                                 unsigned short* __restrict__ h,
                                                 const int* __restrict__ src,
                                                 const int* __restrict__ dst,
                                                 const float* __restrict__ w,
                                                 int* __restrict__ cnt,
                                                 int2* __restrict__ edata) {
    __shared__ short Asm[2][256 * 8];     //  8 KB: slot = g*64 + (row ^ (g<<1))
    __shared__ short Bsm[2][1024 * 8];    // 32 KB: slot = g*256 + n

    const int bid = blockIdx.x;
    const int tid = threadIdx.x;
    const int r3 = bid % 3;
    const int grp = bid / 3;

    if (r3 != 0) {
        // ---- bucket fill (cnt pre-zeroed by prep) ----
        const int fid = grp * 2 + (r3 - 1);
        const int e = fid * 512 + tid;
        if (e < E_EDGES) {
            const int d = dst[e];
            const int pos = atomicAdd(&cnt[d], 1);
            if (pos < CAP) edata[(size_t)d * CAP + pos] = make_int2(src[e], __float_as_int(w[e]));
        }
        return;
    }

    const int m0 = grp * 64;
    const int wv = tid >> 6;        // wave 0..7
    const int wr = wv >> 2;         // m-half: rows wr*32..
    const int wc = wv & 3;          // n-quarter: cols wc*64..
    const int lane = tid & 63;
    const int l15 = lane & 15;
    const int kq = lane >> 4;       // k-granule 0..3

    f32x4 acc[2][4];
    #pragma unroll
    for (int fm = 0; fm < 2; ++fm)
        #pragma unroll
        for (int fn = 0; fn < 4; ++fn)
            #pragma unroll
            for (int r = 0; r < 4; ++r) acc[fm][fn][r] = 0.f;

    float bb[4];
    #pragma unroll
    for (int fn = 0; fn < 4; ++fn) bb[fn] = b[wc * 64 + fn * 16 + l15];

    // A read offsets (swizzled granule-major), const per thread
    int aoff[2];
    #pragma unroll
    for (int fm = 0; fm < 2; ++fm)
        aoff[fm] = (kq * 64 + ((wr * 32 + fm * 16 + l15) ^ (kq << 1))) * 8;

    // A staging (threads 0..255): row = tid>>2 (4 lanes = 128 B coalesced), granule = tid&3.
    const int arow = tid >> 2;      // 0..63
    const int ag = tid & 3;
    int xr = m0 + arow;
    if (xr >= M_NODES) xr = M_NODES - 1;
    const float* xp = x + (size_t)xr * K_DIM + ag * 8;
    const bool do_a = (tid < 256);
    const int aslot = (ag * 64 + (arow ^ (ag << 1))) * 8;   // swizzled write slot

    float4 a4[2][2];   // depth-2 pipeline, statically indexed under full unroll

    auto stageB = [&](int buf, int k0) {
        const unsigned short* wsrc = WTg + (size_t)(k0 >> 5) * 8192;   // kb*4*256*8
        #pragma unroll
        for (int r = 0; r < 2; ++r) {
            const int slot = r * 512 + tid;       // granule-major, lane-consecutive
            gload_lds16(wsrc + slot * 8, &Bsm[buf][slot * 8]);
        }
    };
    auto loadA = [&](int sl, int k0) {
        if (do_a) {
            a4[sl][0] = *reinterpret_cast<const float4*>(xp + k0);
            a4[sl][1] = *reinterpret_cast<const float4*>(xp + k0 + 4);
        }
    };
    auto writeA = [&](int buf, int sl) {
        if (do_a) {
            short8 s0;
            s0[0] = (short)f2bf(a4[sl][0].x); s0[1] = (short)f2bf(a4[sl][0].y);
            s0[2] = (short)f2bf(a4[sl][0].z); s0[3] = (short)f2bf(a4[sl][0].w);
            s0[4] = (short)f2bf(a4[sl][1].x); s0[5] = (short)f2bf(a4[sl][1].y);
            s0[6] = (short)f2bf(a4[sl][1].z); s0[7] = (short)f2bf(a4[sl][1].w);
            *reinterpret_cast<short8*>(&Asm[buf][aslot]) = s0;
        }
    };
    auto compute = [&](int buf) {
        short8 af[2], bf_[4];
        #pragma unroll
        for (int fm = 0; fm < 2; ++fm)
            af[fm] = *reinterpret_cast<const short8*>(&Asm[buf][aoff[fm]]);
        #pragma unroll
        for (int fn = 0; fn < 4; ++fn)
            bf_[fn] = *reinterpret_cast<const short8*>(&Bsm[buf][(kq * 256 + wc * 64 + fn * 16 + l15) * 8]);
        #pragma unroll
        for (int fm = 0; fm < 2; ++fm)
            #pragma unroll
            for (int fn = 0; fn < 4; ++fn)
                acc[fm][fn] = __builtin_amdgcn_mfma_f32_16x16x32_bf16(af[fm], bf_[fn], acc[fm][fn], 0, 0, 0);
    };

    // prologue: buf0 ready; a4[1] pre-loaded with k1
    stageB(0, 0);
    loadA(0, 0);
    writeA(0, 0);
    loadA(1, 32);
    __syncthreads();

    #pragma unroll
    for (int t = 0; t < 16; ++t) {
        const int buf = t & 1;
        const int cur = t & 1;
        if (t < 14) loadA(cur, (t + 2) * 32);    // issue k_{t+2} early (2-deep)
        if (t < 15) stageB(buf ^ 1, (t + 1) * 32);
        compute(buf);
        if (t < 15) writeA(buf ^ 1, cur ^ 1);    // a4[cur^1] holds k_{t+1}
        __syncthreads();
    }

    // epilogue: C layout col=lane&15, row=(lane>>4)*4+r
    #pragma unroll
    for (int fm = 0; fm < 2; ++fm) {
        const int gm = m0 + wr * 32 + fm * 16 + kq * 4;
        #pragma unroll
        for (int r = 0; r < 4; ++r) {
            if (gm + r < M_NODES) {
                #pragma unroll
                for (int fn = 0; fn < 4; ++fn) {
                    const int gn = wc * 64 + fn * 16 + l15;
                    h[(size_t)(gm + r) * N_DIM + gn] = f2bf(acc[fm][fn][r] + bb[fn]);
                }
            }
        }
    }
}

// ---------------- k3: gather, 32 lanes/node, 8-edge unroll, int4 edge loads ----------------
#define ACC8(v, wq)                                        \
    acc[0] += wq * __uint_as_float(v.x << 16);             \
    acc[1] += wq * __uint_as_float(v.x & 0xffff0000u);     \
    acc[2] += wq * __uint_as_float(v.y << 16);             \
    acc[3] += wq * __uint_as_float(v.y & 0xffff0000u);     \
    acc[4] += wq * __uint_as_float(v.z << 16);             \
    acc[5] += wq * __uint_as_float(v.z & 0xffff0000u);     \
    acc[6] += wq * __uint_as_float(v.w << 16);             \
    acc[7] += wq * __uint_as_float(v.w & 0xffff0000u);

__global__ __launch_bounds__(256) void gather_kernel(const unsigned short* __restrict__ h,
                                                     const int* __restrict__ cnt,
                                                     const int2* __restrict__ edata,
                                                     float* __restrict__ out) {
    const int node = blockIdx.x * 8 + (threadIdx.x >> 5);
    const int lane = threadIdx.x & 31;

    int m = cnt[node];
    if (m > CAP) m = CAP;
    const int2* ep = edata + (size_t)node * CAP;

    float acc[8];
    #pragma unroll
    for (int i = 0; i < 8; ++i) acc[i] = 0.f;

    const unsigned short* hb = h + lane * 8;

    int j = 0;
    for (; j + 7 < m; j += 8) {
        int4 e2[4];
        #pragma unroll
        for (int q = 0; q < 4; ++q)
            e2[q] = *reinterpret_cast<const int4*>(ep + j + q * 2);
        uint4 v[8];
        #pragma unroll
        for (int q = 0; q < 4; ++q) {
            v[q * 2]     = *reinterpret_cast<const uint4*>(hb + (size_t)e2[q].x * N_DIM);
            v[q * 2 + 1] = *reinterpret_cast<const uint4*>(hb + (size_t)e2[q].z * N_DIM);
        }
        #pragma unroll
        for (int q = 0; q < 4; ++q) {
            const float w0 = __int_as_float(e2[q].y);
            const float w1 = __int_as_float(e2[q].w);
            ACC8(v[q * 2], w0);
            ACC8(v[q * 2 + 1], w1);
        }
    }
    for (; j + 1 < m; j += 2) {
        const int4 e2 = *reinterpret_cast<const int4*>(ep + j);
        const uint4 v0 = *reinterpret_cast<const uint4*>(hb + (size_t)e2.x * N_DIM);
        const uint4 v1 = *reinterpret_cast<const uint4*>(hb + (size_t)e2.z * N_DIM);
        ACC8(v0, __int_as_float(e2.y));
        ACC8(v1, __int_as_float(e2.w));
    }
    if (j < m) {
        const int2 e0 = ep[j];
        const uint4 v = *reinterpret_cast<const uint4*>(hb + (size_t)e0.x * N_DIM);
        ACC8(v, __int_as_float(e0.y));
    }

    float* op = out + (size_t)node * N_DIM + lane * 8;
    *reinterpret_cast<float4*>(op) = make_float4(acc[0], acc[1], acc[2], acc[3]);
    *reinterpret_cast<float4*>(op + 4) = make_float4(acc[4], acc[5], acc[6], acc[7]);
}

extern "C" void kernel_launch(void* const* d_in, const int* in_sizes, int n_in,
                              void* d_out, int out_size, void* d_ws, size_t ws_size,
                              hipStream_t stream) {
    const float* x   = (const float*)d_in[0];
    const int*   src = (const int*)d_in[1];
    const int*   dst = (const int*)d_in[2];
    const float* w   = (const float*)d_in[3];
    const float* Wm  = (const float*)d_in[4];
    const float* b   = (const float*)d_in[5];
    float* out = (float*)d_out;

    // Workspace layout (bytes)
    char* ws = (char*)d_ws;
    unsigned short* WTg = (unsigned short*)(ws + 0);           //    262,144 (tiled)
    unsigned short* h   = (unsigned short*)(ws + 262144);      // 25,600,000
    int*  cnt   = (int*)(ws + 25862144);                       //    200,000
    int2* edata = (int2*)(ws + 26062144);                      // 25,600,000 (end ~51.7 MB)

    // k1: build tiled WTg + zero cnt
    prep_kernel<<<512 + (M_NODES + 255) / 256, 256, 0, stream>>>(Wm, WTg, cnt);

    // k2: projection with interleaved bucket fill
    gemm_fill<<<GRID, 512, 0, stream>>>(x, WTg, b, h, src, dst, w, cnt, edata);

    // k3: aggregate
    gather_kernel<<<M_NODES / 8, 256, 0, stream>>>(h, cnt, edata, out);
}